// Round 8
// baseline (85.750 us; speedup 1.0000x reference)
//
#include <hip/hip_runtime.h>
#include <hip/hip_bf16.h>

// Problem sizes (fixed by the reference)
#define S_LEN 256     // sequence length (t)
#define DM    512     // d_model (k / d)
#define DR    512     // d_rnn (s)
#define PF    8       // register prefetch depth (t-steps)

typedef float f4 __attribute__((ext_vector_type(4)));
typedef float f2 __attribute__((ext_vector_type(2)));

// ws layout (floats):
//   xT  : [512][256]     at 0       (131072)
//   acT : f2[512][256]   at 131072  (262144)

__global__ __launch_bounds__(256) void k_transpose_x(const float* __restrict__ x,
                                                     float* __restrict__ xT) {
    __shared__ float tile[32][33];
    const int k0 = blockIdx.x * 32;
    const int t0 = blockIdx.y * 32;
    const int lx = threadIdx.x & 31;
    const int ly = threadIdx.x >> 5;
#pragma unroll
    for (int i = 0; i < 32; i += 8)
        tile[ly + i][lx] = x[(t0 + ly + i) * DM + k0 + lx];
    __syncthreads();
#pragma unroll
    for (int i = 0; i < 32; i += 8)
        xT[(k0 + ly + i) * S_LEN + t0 + lx] = tile[lx][ly + i];
}

// grid(128): block g -> GEMM rows {4g..4g+3, 512+4g..512+4g+3}; epilogue writes acT.
__global__ __launch_bounds__(256) void k_gemm_act(const float* __restrict__ xT,
                                                  const float* __restrict__ W1,
                                                  const float* __restrict__ b1,
                                                  const float* __restrict__ Lam,
                                                  f2* __restrict__ acT) {
    const int g  = blockIdx.x;       // 0..127
    const int t  = threadIdx.x;      // lane axis = t (coalesced xT loads)
    const int r0 = 4 * g;

    float ai[4] = {0.f, 0.f, 0.f, 0.f};
    float ar[4] = {0.f, 0.f, 0.f, 0.f};
    const float* __restrict__ xb = xT + t;

#pragma unroll 8
    for (int k = 0; k < DM; ++k) {
        const float xv = xb[k * S_LEN];
#pragma unroll
        for (int j = 0; j < 4; ++j) {
            ai[j] = fmaf(xv, W1[(r0 + j) * DM + k], ai[j]);        // wave-uniform
            ar[j] = fmaf(xv, W1[(512 + r0 + j) * DM + k], ar[j]);
        }
    }

#pragma unroll
    for (int j = 0; j < 4; ++j) {
        const float pre_i = ai[j] + b1[r0 + j];
        const float pre_r = ar[j] + b1[512 + r0 + j];
        const float inp = 1.f / (1.f + expf(-pre_i));
        const float rec = 1.f / (1.f + expf(-pre_r));
        const float sp  = log1pf(expf(Lam[r0 + j]));
        const float a   = expf(-8.f * sp * rec);
        const float c   = sqrtf(fmaxf(1.f - a * a, 0.f)) * inp;
        f2 ac; ac.x = a; ac.y = c;
        acT[(r0 + j) * S_LEN + t] = ac;
    }
}

// grid(256) x 256: block = s-pair, full t sweep. 8-deep rolling register
// prefetch of x: the load consumed at step t was issued at step t-8, so the
// vmcnt wait at consume time leaves ~8 stores outstanding per wave
// (in-flight ~32 KB/CU -> HBM-write-latency covered, stores stream at drain
// rate). No LDS for x, no barriers in the loop.
__global__ __launch_bounds__(256) void k_rec(const float* __restrict__ x,
                                             const float* __restrict__ state0,
                                             const f2* __restrict__ acT,
                                             f4* __restrict__ out4) {
    const int bx   = blockIdx.x;         // s-pair
    const int tid  = threadIdx.x;
    const int sloc = tid >> 7;           // 0..1
    const int dq   = tid & 127;          // 0..127
    const int s    = bx * 2 + sloc;

    __shared__ f2 ac_l[2][S_LEN];        // 4 KB

    // stage a,c for both s rows (512 f2, 2 per thread)
#pragma unroll
    for (int i = 0; i < 2; ++i) {
        const int idx = i * 256 + tid;
        const int sl = idx >> 8, tt = idx & 255;
        ac_l[sl][tt] = acT[(bx * 2 + sl) * S_LEN + tt];
    }

    const f4* __restrict__ x4  = reinterpret_cast<const f4*>(x);
    const f4* __restrict__ st4 = reinterpret_cast<const f4*>(state0);
    f4 h = st4[s * 128 + dq];

    // prologue: fill the 8-deep pipeline
    f4 xr0 = x4[0 * 128 + dq];
    f4 xr1 = x4[1 * 128 + dq];
    f4 xr2 = x4[2 * 128 + dq];
    f4 xr3 = x4[3 * 128 + dq];
    f4 xr4 = x4[4 * 128 + dq];
    f4 xr5 = x4[5 * 128 + dq];
    f4 xr6 = x4[6 * 128 + dq];
    f4 xr7 = x4[7 * 128 + dq];

    __syncthreads();   // ac_l ready (before any y store is outstanding)

#define STEP(I)                                                              \
    {                                                                        \
        const int t = tb + (I);                                              \
        const f2 ac = ac_l[sloc][t];           /* wave-uniform LDS */        \
        const f4 xv = xr##I;                   /* vmcnt wait: 8 stores ok */ \
        h.x = fmaf(ac.x, h.x, ac.y * xv.x);                                  \
        h.y = fmaf(ac.x, h.y, ac.y * xv.y);                                  \
        h.z = fmaf(ac.x, h.z, ac.y * xv.z);                                  \
        h.w = fmaf(ac.x, h.w, ac.y * xv.w);                                  \
        if (t + PF < S_LEN) xr##I = x4[(t + PF) * 128 + dq];                 \
        __builtin_nontemporal_store(h, &out4[(t * DR + s) * 128 + dq]);      \
    }

    for (int tb = 0; tb < S_LEN; tb += PF) {
        STEP(0) STEP(1) STEP(2) STEP(3) STEP(4) STEP(5) STEP(6) STEP(7)
    }
#undef STEP

    // final state
    out4[(S_LEN * DR) * 128 + s * 128 + dq] = h;
}

extern "C" void kernel_launch(void* const* d_in, const int* in_sizes, int n_in,
                              void* d_out, int out_size, void* d_ws, size_t ws_size,
                              hipStream_t stream) {
    const float* x      = (const float*)d_in[0];
    const float* state0 = (const float*)d_in[1];
    const float* W1     = (const float*)d_in[2];
    const float* b1     = (const float*)d_in[3];
    const float* Lam    = (const float*)d_in[4];

    float* ws  = (float*)d_ws;
    float* xT  = ws;                      // 131072 floats
    f2*    acT = (f2*)(ws + 131072);      // 131072 f2

    f4* out4 = (f4*)d_out;

    k_transpose_x<<<dim3(16, 8), 256, 0, stream>>>(x, xT);
    k_gemm_act<<<dim3(128), 256, 0, stream>>>(xT, W1, b1, Lam, acT);
    k_rec<<<dim3(256), 256, 0, stream>>>(x, state0, acT, out4);
}